// Round 2
// baseline (63.793 us; speedup 1.0000x reference)
//
#include <hip/hip_runtime.h>
#include <hip/hip_bf16.h>

#define EMB 64

typedef __attribute__((ext_vector_type(8))) short short8;
typedef __attribute__((ext_vector_type(8))) __bf16 bf16x8;
typedef __attribute__((ext_vector_type(4))) float f32x4;

__device__ inline f32x4 mfma16x16x32(short8 a, short8 b, f32x4 c) {
  return __builtin_amdgcn_mfma_f32_16x16x32_bf16(
      __builtin_bit_cast(bf16x8, a), __builtin_bit_cast(bf16x8, b), c, 0, 0, 0);
}

// Clears the 200,000-byte flag region (12,500 uint4) — replaces the
// pathologically slow runtime fillBuffer path (was 40 µs for 195 KB).
__global__ __launch_bounds__(256) void clear_kernel(uint4* __restrict__ p) {
  const int i = blockIdx.x * 256 + threadIdx.x;
  if (i < 12500) p[i] = make_uint4(0u, 0u, 0u, 0u);
}

// One wave per batch row: gather, l2-normalize, store bf16, per-row 'up' term,
// set unique-flags.
__global__ __launch_bounds__(256) void prep_kernel(
    const int* __restrict__ user, const int* __restrict__ pos,
    const float* __restrict__ uw, const float* __restrict__ iw,
    __hip_bfloat16* __restrict__ u_bf, __hip_bfloat16* __restrict__ p_bf,
    unsigned char* __restrict__ uflag, unsigned char* __restrict__ iflag,
    float* __restrict__ up_partials)
{
  const int wave = threadIdx.x >> 6;
  const int lane = threadIdx.x & 63;
  const int row  = (blockIdx.x << 2) + wave;

  const int uidx = user[row];
  const int pidx = pos[row];
  float uv = uw[uidx * EMB + lane];
  float pv = iw[pidx * EMB + lane];

  float us = uv * uv, ps = pv * pv;
  #pragma unroll
  for (int off = 32; off; off >>= 1) {
    us += __shfl_xor(us, off);
    ps += __shfl_xor(ps, off);
  }
  const float un = uv / fmaxf(sqrtf(us), 1e-12f);
  const float pn = pv / fmaxf(sqrtf(ps), 1e-12f);
  u_bf[row * EMB + lane] = __float2bfloat16(un);
  p_bf[row * EMB + lane] = __float2bfloat16(pn);

  float ipv = un * pn;
  #pragma unroll
  for (int off = 32; off; off >>= 1) ipv += __shfl_xor(ipv, off);

  __shared__ float sred[4];
  if (lane == 0) {
    uflag[uidx] = 1;
    iflag[pidx] = 1;
    // log(exp(ip/T) + exp(ip*ip/T)), T = 0.2
    sred[wave] = logf(expf(ipv * 5.0f) + expf(ipv * ipv * 5.0f));
  }
  __syncthreads();
  if (threadIdx.x == 0)
    up_partials[blockIdx.x] = (sred[0] + sred[1]) + (sred[2] + sred[3]);
}

// 128x128 output tile per block, 4 waves in 2x2, each wave a 64x64 subtile.
// K = 64 total (2 MFMA k-steps). Fragments loaded straight from global
// (operands are 1 MB each -> L2 resident). Epilogue: sum exp(v/T)+exp(v^2/T)
// over all tile elements -> one partial per block.
__global__ __launch_bounds__(256) void gemm_kernel(
    const __hip_bfloat16* __restrict__ U, const __hip_bfloat16* __restrict__ P,
    float* __restrict__ down_partials)
{
  const int bx = blockIdx.x & 63;
  const int by = blockIdx.x >> 6;
  const int wave = threadIdx.x >> 6;
  const int lane = threadIdx.x & 63;
  const int r0 = by * 128 + (wave >> 1) * 64;
  const int c0 = bx * 128 + (wave & 1) * 64;
  const int lrow = lane & 15;
  const int lk   = (lane >> 4) * 8;

  short8 a[4][2], b[4][2];
  #pragma unroll
  for (int i = 0; i < 4; ++i) {
    #pragma unroll
    for (int kk = 0; kk < 2; ++kk) {
      a[i][kk] = *reinterpret_cast<const short8*>(&U[(size_t)(r0 + i * 16 + lrow) * EMB + kk * 32 + lk]);
      b[i][kk] = *reinterpret_cast<const short8*>(&P[(size_t)(c0 + i * 16 + lrow) * EMB + kk * 32 + lk]);
    }
  }

  f32x4 acc[4][4] = {};
  #pragma unroll
  for (int i = 0; i < 4; ++i) {
    #pragma unroll
    for (int j = 0; j < 4; ++j) {
      acc[i][j] = mfma16x16x32(a[i][0], b[j][0], acc[i][j]);
      acc[i][j] = mfma16x16x32(a[i][1], b[j][1], acc[i][j]);
    }
  }

  // exp(v/T) = exp2(v * 5*log2e); exp(v^2/T) = exp2(v * (v * 5*log2e))
  const float C = 7.213475204444817f;  // 5 * log2(e)
  float s = 0.0f;
  #pragma unroll
  for (int i = 0; i < 4; ++i) {
    #pragma unroll
    for (int j = 0; j < 4; ++j) {
      #pragma unroll
      for (int r = 0; r < 4; ++r) {
        const float v = acc[i][j][r];
        const float t = v * C;
        s += exp2f(t) + exp2f(v * t);
      }
    }
  }
  #pragma unroll
  for (int off = 32; off; off >>= 1) s += __shfl_xor(s, off);

  __shared__ float sred[4];
  if (lane == 0) sred[wave] = s;
  __syncthreads();
  if (threadIdx.x == 0)
    down_partials[blockIdx.x] = (sred[0] + sred[1]) + (sred[2] + sred[3]);
}

// Single-block deterministic final reduction.
__global__ __launch_bounds__(1024) void finalize_kernel(
    const float* __restrict__ up_partials, const float* __restrict__ down_partials,
    const uint4* __restrict__ uflag4, const uint4* __restrict__ iflag4,
    float* __restrict__ out)
{
  const int tid = threadIdx.x;
  float upv = 0.0f;
  for (int i = tid; i < 2048; i += 1024) upv += up_partials[i];
  float dnv = 0.0f;
  for (int i = tid; i < 4096; i += 1024) dnv += down_partials[i];
  int uc = 0, ic = 0;
  for (int i = tid; i < 6250; i += 1024) {   // 100000 bytes = 6250 * 16
    uint4 v = uflag4[i];
    uc += __popc(v.x) + __popc(v.y) + __popc(v.z) + __popc(v.w);
    uint4 w = iflag4[i];
    ic += __popc(w.x) + __popc(w.y) + __popc(w.z) + __popc(w.w);
  }

  __shared__ float rf[1024];
  __shared__ int   ri[1024];

  rf[tid] = upv; __syncthreads();
  for (int s = 512; s; s >>= 1) { if (tid < s) rf[tid] += rf[tid + s]; __syncthreads(); }
  const float up_sum = rf[0]; __syncthreads();

  rf[tid] = dnv; __syncthreads();
  for (int s = 512; s; s >>= 1) { if (tid < s) rf[tid] += rf[tid + s]; __syncthreads(); }
  const float dn_sum = rf[0]; __syncthreads();

  ri[tid] = uc; __syncthreads();
  for (int s = 512; s; s >>= 1) { if (tid < s) ri[tid] += ri[tid + s]; __syncthreads(); }
  const int nu = ri[0]; __syncthreads();

  ri[tid] = ic; __syncthreads();
  for (int s = 512; s; s >>= 1) { if (tid < s) ri[tid] += ri[tid + s]; __syncthreads(); }
  const int ni = ri[0];

  if (tid == 0) {
    out[0] = -(up_sum / 8192.0f);
    out[1] = logf(dn_sum / ((float)nu * (float)ni));
  }
}

extern "C" void kernel_launch(void* const* d_in, const int* in_sizes, int n_in,
                              void* d_out, int out_size, void* d_ws, size_t ws_size,
                              hipStream_t stream) {
  const int*   user = (const int*)d_in[0];
  const int*   pos  = (const int*)d_in[1];
  // d_in[2] = negative (unused by the reference loss)
  const float* uw   = (const float*)d_in[3];
  const float* iw   = (const float*)d_in[4];
  float* out = (float*)d_out;

  char* ws = (char*)d_ws;
  __hip_bfloat16* u_bf = (__hip_bfloat16*)(ws);
  __hip_bfloat16* p_bf = (__hip_bfloat16*)(ws + (1u << 20));
  unsigned char*  uflag = (unsigned char*)(ws + (2u << 20));
  unsigned char*  iflag = uflag + 100000;                    // offsets stay 16B aligned
  float* up_partials   = (float*)(ws + (2u << 20) + 200000);
  float* down_partials = up_partials + 2048;

  clear_kernel<<<49, 256, 0, stream>>>((uint4*)uflag);       // clears uflag+iflag (200 KB)
  prep_kernel<<<2048, 256, 0, stream>>>(user, pos, uw, iw, u_bf, p_bf,
                                        uflag, iflag, up_partials);
  gemm_kernel<<<64 * 64, 256, 0, stream>>>(u_bf, p_bf, down_partials);
  finalize_kernel<<<1, 1024, 0, stream>>>(up_partials, down_partials,
                                          (const uint4*)uflag, (const uint4*)iflag, out);
}

// Round 3
// 55.841 us; speedup vs baseline: 1.1424x; 1.1424x over previous
//
#include <hip/hip_runtime.h>
#include <hip/hip_bf16.h>

#define EMB 64

typedef __attribute__((ext_vector_type(8))) short short8;
typedef __attribute__((ext_vector_type(8))) __bf16 bf16x8;
typedef __attribute__((ext_vector_type(4))) float f32x4;

__device__ inline f32x4 mfma16x16x32(short8 a, short8 b, f32x4 c) {
  return __builtin_amdgcn_mfma_f32_16x16x32_bf16(
      __builtin_bit_cast(bf16x8, a), __builtin_bit_cast(bf16x8, b), c, 0, 0, 0);
}

// Clears the 200,000-byte flag region (12,500 uint4) — replaces the
// pathologically slow runtime fillBuffer path (was 40 µs for 195 KB).
__global__ __launch_bounds__(256) void clear_kernel(uint4* __restrict__ p) {
  const int i = blockIdx.x * 256 + threadIdx.x;
  if (i < 12500) p[i] = make_uint4(0u, 0u, 0u, 0u);
}

// One wave per batch row: gather, l2-normalize, store bf16, per-row 'up' term,
// set unique-flags.
__global__ __launch_bounds__(256) void prep_kernel(
    const int* __restrict__ user, const int* __restrict__ pos,
    const float* __restrict__ uw, const float* __restrict__ iw,
    __hip_bfloat16* __restrict__ u_bf, __hip_bfloat16* __restrict__ p_bf,
    unsigned char* __restrict__ uflag, unsigned char* __restrict__ iflag,
    float* __restrict__ up_partials)
{
  const int wave = threadIdx.x >> 6;
  const int lane = threadIdx.x & 63;
  const int row  = (blockIdx.x << 2) + wave;

  const int uidx = user[row];
  const int pidx = pos[row];
  float uv = uw[uidx * EMB + lane];
  float pv = iw[pidx * EMB + lane];

  float us = uv * uv, ps = pv * pv;
  #pragma unroll
  for (int off = 32; off; off >>= 1) {
    us += __shfl_xor(us, off);
    ps += __shfl_xor(ps, off);
  }
  const float un = uv / fmaxf(sqrtf(us), 1e-12f);
  const float pn = pv / fmaxf(sqrtf(ps), 1e-12f);
  u_bf[row * EMB + lane] = __float2bfloat16(un);
  p_bf[row * EMB + lane] = __float2bfloat16(pn);

  float ipv = un * pn;
  #pragma unroll
  for (int off = 32; off; off >>= 1) ipv += __shfl_xor(ipv, off);

  __shared__ float sred[4];
  if (lane == 0) {
    uflag[uidx] = 1;
    iflag[pidx] = 1;
    // log(exp(ip/T) + exp(ip*ip/T)), T = 0.2
    sred[wave] = logf(__expf(ipv * 5.0f) + __expf(ipv * ipv * 5.0f));
  }
  __syncthreads();
  if (threadIdx.x == 0)
    up_partials[blockIdx.x] = (sred[0] + sred[1]) + (sred[2] + sred[3]);
}

// 128x128 output tile per block, 4 waves in 2x2, each wave a 64x64 subtile.
// K = 64 total (2 MFMA k-steps). Fragments loaded straight from global
// (operands are ~1 MB each -> L2/L3 resident). Epilogue: sum
// exp(v/T)+exp(v^2/T) over all tile elements -> one partial per block.
// NOTE: __expf (native v_exp_f32) — exp2f lowers to the slow OCML precise
// path and cost 4x on this kernel (round-2 lesson).
__global__ __launch_bounds__(256) void gemm_kernel(
    const __hip_bfloat16* __restrict__ U, const __hip_bfloat16* __restrict__ P,
    float* __restrict__ down_partials)
{
  const int bx = blockIdx.x & 63;
  const int by = blockIdx.x >> 6;
  const int wave = threadIdx.x >> 6;
  const int lane = threadIdx.x & 63;
  const int r0 = by * 128 + (wave >> 1) * 64;
  const int c0 = bx * 128 + (wave & 1) * 64;
  const int lrow = lane & 15;
  const int lk   = (lane >> 4) * 8;

  short8 a[4][2], b[4][2];
  #pragma unroll
  for (int i = 0; i < 4; ++i) {
    #pragma unroll
    for (int kk = 0; kk < 2; ++kk) {
      a[i][kk] = *reinterpret_cast<const short8*>(&U[(size_t)(r0 + i * 16 + lrow) * EMB + kk * 32 + lk]);
      b[i][kk] = *reinterpret_cast<const short8*>(&P[(size_t)(c0 + i * 16 + lrow) * EMB + kk * 32 + lk]);
    }
  }

  f32x4 acc[4][4] = {};
  #pragma unroll
  for (int i = 0; i < 4; ++i) {
    #pragma unroll
    for (int j = 0; j < 4; ++j) {
      acc[i][j] = mfma16x16x32(a[i][0], b[j][0], acc[i][j]);
      acc[i][j] = mfma16x16x32(a[i][1], b[j][1], acc[i][j]);
    }
  }

  float s = 0.0f;
  #pragma unroll
  for (int i = 0; i < 4; ++i) {
    #pragma unroll
    for (int j = 0; j < 4; ++j) {
      #pragma unroll
      for (int r = 0; r < 4; ++r) {
        const float v  = acc[i][j][r];
        const float v5 = v * 5.0f;           // v / T
        s += __expf(v5) + __expf(v * v5);    // exp(v/T) + exp(v^2/T)
      }
    }
  }
  #pragma unroll
  for (int off = 32; off; off >>= 1) s += __shfl_xor(s, off);

  __shared__ float sred[4];
  if (lane == 0) sred[wave] = s;
  __syncthreads();
  if (threadIdx.x == 0)
    down_partials[blockIdx.x] = (sred[0] + sred[1]) + (sred[2] + sred[3]);
}

// Single-block deterministic final reduction.
__global__ __launch_bounds__(1024) void finalize_kernel(
    const float* __restrict__ up_partials, const float* __restrict__ down_partials,
    const uint4* __restrict__ uflag4, const uint4* __restrict__ iflag4,
    float* __restrict__ out)
{
  const int tid = threadIdx.x;
  float upv = 0.0f;
  for (int i = tid; i < 2048; i += 1024) upv += up_partials[i];
  float dnv = 0.0f;
  for (int i = tid; i < 4096; i += 1024) dnv += down_partials[i];
  int uc = 0, ic = 0;
  for (int i = tid; i < 6250; i += 1024) {   // 100000 bytes = 6250 * 16
    uint4 v = uflag4[i];
    uc += __popc(v.x) + __popc(v.y) + __popc(v.z) + __popc(v.w);
    uint4 w = iflag4[i];
    ic += __popc(w.x) + __popc(w.y) + __popc(w.z) + __popc(w.w);
  }

  __shared__ float rf[1024];
  __shared__ int   ri[1024];

  rf[tid] = upv; __syncthreads();
  for (int s = 512; s; s >>= 1) { if (tid < s) rf[tid] += rf[tid + s]; __syncthreads(); }
  const float up_sum = rf[0]; __syncthreads();

  rf[tid] = dnv; __syncthreads();
  for (int s = 512; s; s >>= 1) { if (tid < s) rf[tid] += rf[tid + s]; __syncthreads(); }
  const float dn_sum = rf[0]; __syncthreads();

  ri[tid] = uc; __syncthreads();
  for (int s = 512; s; s >>= 1) { if (tid < s) ri[tid] += ri[tid + s]; __syncthreads(); }
  const int nu = ri[0]; __syncthreads();

  ri[tid] = ic; __syncthreads();
  for (int s = 512; s; s >>= 1) { if (tid < s) ri[tid] += ri[tid + s]; __syncthreads(); }
  const int ni = ri[0];

  if (tid == 0) {
    out[0] = -(up_sum / 8192.0f);
    out[1] = logf(dn_sum / ((float)nu * (float)ni));
  }
}

extern "C" void kernel_launch(void* const* d_in, const int* in_sizes, int n_in,
                              void* d_out, int out_size, void* d_ws, size_t ws_size,
                              hipStream_t stream) {
  const int*   user = (const int*)d_in[0];
  const int*   pos  = (const int*)d_in[1];
  // d_in[2] = negative (unused by the reference loss)
  const float* uw   = (const float*)d_in[3];
  const float* iw   = (const float*)d_in[4];
  float* out = (float*)d_out;

  char* ws = (char*)d_ws;
  __hip_bfloat16* u_bf = (__hip_bfloat16*)(ws);
  __hip_bfloat16* p_bf = (__hip_bfloat16*)(ws + (1u << 20));
  unsigned char*  uflag = (unsigned char*)(ws + (2u << 20));
  unsigned char*  iflag = uflag + 100000;                    // offsets stay 16B aligned
  float* up_partials   = (float*)(ws + (2u << 20) + 200000);
  float* down_partials = up_partials + 2048;

  clear_kernel<<<49, 256, 0, stream>>>((uint4*)uflag);       // clears uflag+iflag (200 KB)
  prep_kernel<<<2048, 256, 0, stream>>>(user, pos, uw, iw, u_bf, p_bf,
                                        uflag, iflag, up_partials);
  gemm_kernel<<<64 * 64, 256, 0, stream>>>(u_bf, p_bf, down_partials);
  finalize_kernel<<<1, 1024, 0, stream>>>(up_partials, down_partials,
                                          (const uint4*)uflag, (const uint4*)iflag, out);
}

// Round 4
// 53.770 us; speedup vs baseline: 1.1864x; 1.0385x over previous
//
#include <hip/hip_runtime.h>
#include <hip/hip_bf16.h>

#define EMB 64

typedef __attribute__((ext_vector_type(8))) short short8;
typedef __attribute__((ext_vector_type(8))) __bf16 bf16x8;
typedef __attribute__((ext_vector_type(4))) float f32x4;

__device__ inline f32x4 mfma16x16x32(short8 a, short8 b, f32x4 c) {
  return __builtin_amdgcn_mfma_f32_16x16x32_bf16(
      __builtin_bit_cast(bf16x8, a), __builtin_bit_cast(bf16x8, b), c, 0, 0, 0);
}

// exp(x/T) via raw v_exp_f32 (2^x). __expf/exp2f both lower to multi-instr
// OCML expansions on this toolchain (~30 VALU ops/elem — rounds 1-3 lesson);
// __builtin_amdgcn_exp2f is the single-instruction hardware path.
#define EXP2_HW __builtin_amdgcn_exp2f
#define C5LOG2E 7.213475204444817f  // 5 * log2(e)

// Clears the 200,000-byte flag region (12,500 uint4).
__global__ __launch_bounds__(256) void clear_kernel(uint4* __restrict__ p) {
  const int i = blockIdx.x * 256 + threadIdx.x;
  if (i < 12500) p[i] = make_uint4(0u, 0u, 0u, 0u);
}

// One wave per batch row: gather, l2-normalize, store bf16, per-row 'up' term,
// set unique-flags.
__global__ __launch_bounds__(256) void prep_kernel(
    const int* __restrict__ user, const int* __restrict__ pos,
    const float* __restrict__ uw, const float* __restrict__ iw,
    __hip_bfloat16* __restrict__ u_bf, __hip_bfloat16* __restrict__ p_bf,
    unsigned char* __restrict__ uflag, unsigned char* __restrict__ iflag,
    float* __restrict__ up_partials)
{
  const int wave = threadIdx.x >> 6;
  const int lane = threadIdx.x & 63;
  const int row  = (blockIdx.x << 2) + wave;

  const int uidx = user[row];
  const int pidx = pos[row];
  float uv = uw[uidx * EMB + lane];
  float pv = iw[pidx * EMB + lane];

  float us = uv * uv, ps = pv * pv;
  #pragma unroll
  for (int off = 32; off; off >>= 1) {
    us += __shfl_xor(us, off);
    ps += __shfl_xor(ps, off);
  }
  const float un = uv / fmaxf(sqrtf(us), 1e-12f);
  const float pn = pv / fmaxf(sqrtf(ps), 1e-12f);
  u_bf[row * EMB + lane] = __float2bfloat16(un);
  p_bf[row * EMB + lane] = __float2bfloat16(pn);

  float ipv = un * pn;
  #pragma unroll
  for (int off = 32; off; off >>= 1) ipv += __shfl_xor(ipv, off);

  __shared__ float sred[4];
  if (lane == 0) {
    uflag[uidx] = 1;
    iflag[pidx] = 1;
    // log(exp(ip/T) + exp(ip*ip/T)), T = 0.2
    const float t = ipv * C5LOG2E;
    sred[wave] = logf(EXP2_HW(t) + EXP2_HW(ipv * t));
  }
  __syncthreads();
  if (threadIdx.x == 0)
    up_partials[blockIdx.x] = (sred[0] + sred[1]) + (sred[2] + sred[3]);
}

// 128x128 output tile per block, 4 waves in 2x2, each wave a 64x64 subtile.
// K = 64 total (2 MFMA k-steps). Fragments loaded straight from global
// (operands ~1 MB each -> L2 resident). Epilogue: sum exp(v/T)+exp(v^2/T)
// over all tile elements via raw v_exp_f32 -> one partial per block.
__global__ __launch_bounds__(256) void gemm_kernel(
    const __hip_bfloat16* __restrict__ U, const __hip_bfloat16* __restrict__ P,
    float* __restrict__ down_partials)
{
  const int bx = blockIdx.x & 63;
  const int by = blockIdx.x >> 6;
  const int wave = threadIdx.x >> 6;
  const int lane = threadIdx.x & 63;
  const int r0 = by * 128 + (wave >> 1) * 64;
  const int c0 = bx * 128 + (wave & 1) * 64;
  const int lrow = lane & 15;
  const int lk   = (lane >> 4) * 8;

  short8 a[4][2], b[4][2];
  #pragma unroll
  for (int i = 0; i < 4; ++i) {
    #pragma unroll
    for (int kk = 0; kk < 2; ++kk) {
      a[i][kk] = *reinterpret_cast<const short8*>(&U[(size_t)(r0 + i * 16 + lrow) * EMB + kk * 32 + lk]);
      b[i][kk] = *reinterpret_cast<const short8*>(&P[(size_t)(c0 + i * 16 + lrow) * EMB + kk * 32 + lk]);
    }
  }

  f32x4 acc[4][4] = {};
  #pragma unroll
  for (int i = 0; i < 4; ++i) {
    #pragma unroll
    for (int j = 0; j < 4; ++j) {
      acc[i][j] = mfma16x16x32(a[i][0], b[j][0], acc[i][j]);
      acc[i][j] = mfma16x16x32(a[i][1], b[j][1], acc[i][j]);
    }
  }

  // exp(v/T) = 2^(v*C); exp(v^2/T) = 2^(v*(v*C)); C = 5*log2(e), |v| <= 1.
  float s0 = 0.0f, s1 = 0.0f;
  #pragma unroll
  for (int i = 0; i < 4; ++i) {
    #pragma unroll
    for (int j = 0; j < 4; ++j) {
      #pragma unroll
      for (int r = 0; r < 4; ++r) {
        const float v = acc[i][j][r];
        const float t = v * C5LOG2E;
        s0 += EXP2_HW(t);
        s1 += EXP2_HW(v * t);
      }
    }
  }
  float s = s0 + s1;
  #pragma unroll
  for (int off = 32; off; off >>= 1) s += __shfl_xor(s, off);

  __shared__ float sred[4];
  if (lane == 0) sred[wave] = s;
  __syncthreads();
  if (threadIdx.x == 0)
    down_partials[blockIdx.x] = (sred[0] + sred[1]) + (sred[2] + sred[3]);
}

// Single-block deterministic final reduction (shuffle-based, 1 barrier).
__global__ __launch_bounds__(1024) void finalize_kernel(
    const float* __restrict__ up_partials, const float* __restrict__ down_partials,
    const uint4* __restrict__ uflag4, const uint4* __restrict__ iflag4,
    float* __restrict__ out)
{
  const int tid  = threadIdx.x;
  const int wave = tid >> 6;
  const int lane = tid & 63;

  float upv = 0.0f;
  for (int i = tid; i < 2048; i += 1024) upv += up_partials[i];
  float dnv = 0.0f;
  for (int i = tid; i < 4096; i += 1024) dnv += down_partials[i];
  int uc = 0, ic = 0;
  for (int i = tid; i < 6250; i += 1024) {   // 100000 bytes = 6250 * 16
    uint4 v = uflag4[i];
    uc += __popc(v.x) + __popc(v.y) + __popc(v.z) + __popc(v.w);
    uint4 w = iflag4[i];
    ic += __popc(w.x) + __popc(w.y) + __popc(w.z) + __popc(w.w);
  }

  #pragma unroll
  for (int off = 32; off; off >>= 1) {
    upv += __shfl_xor(upv, off);
    dnv += __shfl_xor(dnv, off);
    uc  += __shfl_xor(uc, off);
    ic  += __shfl_xor(ic, off);
  }

  __shared__ float sf[2][16];
  __shared__ int   si[2][16];
  if (lane == 0) { sf[0][wave] = upv; sf[1][wave] = dnv; si[0][wave] = uc; si[1][wave] = ic; }
  __syncthreads();
  if (tid == 0) {
    float usum = 0.0f, dsum = 0.0f; int nu = 0, ni = 0;
    #pragma unroll
    for (int w = 0; w < 16; ++w) {
      usum += sf[0][w]; dsum += sf[1][w]; nu += si[0][w]; ni += si[1][w];
    }
    out[0] = -(usum / 8192.0f);
    out[1] = logf(dsum / ((float)nu * (float)ni));
  }
}

extern "C" void kernel_launch(void* const* d_in, const int* in_sizes, int n_in,
                              void* d_out, int out_size, void* d_ws, size_t ws_size,
                              hipStream_t stream) {
  const int*   user = (const int*)d_in[0];
  const int*   pos  = (const int*)d_in[1];
  // d_in[2] = negative (unused by the reference loss)
  const float* uw   = (const float*)d_in[3];
  const float* iw   = (const float*)d_in[4];
  float* out = (float*)d_out;

  char* ws = (char*)d_ws;
  __hip_bfloat16* u_bf = (__hip_bfloat16*)(ws);
  __hip_bfloat16* p_bf = (__hip_bfloat16*)(ws + (1u << 20));
  unsigned char*  uflag = (unsigned char*)(ws + (2u << 20));
  unsigned char*  iflag = uflag + 100000;                    // offsets stay 16B aligned
  float* up_partials   = (float*)(ws + (2u << 20) + 200000);
  float* down_partials = up_partials + 2048;

  clear_kernel<<<49, 256, 0, stream>>>((uint4*)uflag);       // clears uflag+iflag (200 KB)
  prep_kernel<<<2048, 256, 0, stream>>>(user, pos, uw, iw, u_bf, p_bf,
                                        uflag, iflag, up_partials);
  gemm_kernel<<<64 * 64, 256, 0, stream>>>(u_bf, p_bf, down_partials);
  finalize_kernel<<<1, 1024, 0, stream>>>(up_partials, down_partials,
                                          (const uint4*)uflag, (const uint4*)iflag, out);
}

// Round 5
// 45.666 us; speedup vs baseline: 1.3969x; 1.1775x over previous
//
#include <hip/hip_runtime.h>
#include <hip/hip_bf16.h>

#define EMB 64

typedef __attribute__((ext_vector_type(8))) short short8;
typedef __attribute__((ext_vector_type(8))) __bf16 bf16x8;
typedef __attribute__((ext_vector_type(4))) float f32x4;

__device__ inline f32x4 mfma16x16x32(short8 a, short8 b, f32x4 c) {
  return __builtin_amdgcn_mfma_f32_16x16x32_bf16(
      __builtin_bit_cast(bf16x8, a), __builtin_bit_cast(bf16x8, b), c, 0, 0, 0);
}

// Raw v_exp_f32 (2^x). OCML exp2f cost 4x (round-2); __expf also multi-instr.
#define EXP2_HW __builtin_amdgcn_exp2f
#define C5LOG2E 7.213475204444817f  // 5 * log2(e)

// Clears the 200,000-byte flag region (12,500 uint4).
__global__ __launch_bounds__(256) void clear_kernel(uint4* __restrict__ p) {
  const int i = blockIdx.x * 256 + threadIdx.x;
  if (i < 12500) p[i] = make_uint4(0u, 0u, 0u, 0u);
}

// Grid-stride: 512 blocks x 4 waves, 4 rows per wave. Gather, l2-normalize,
// store bf16, per-row 'up' term, set unique-flags.
__global__ __launch_bounds__(256) void prep_kernel(
    const int* __restrict__ user, const int* __restrict__ pos,
    const float* __restrict__ uw, const float* __restrict__ iw,
    __hip_bfloat16* __restrict__ u_bf, __hip_bfloat16* __restrict__ p_bf,
    unsigned char* __restrict__ uflag, unsigned char* __restrict__ iflag,
    float* __restrict__ up_partials)
{
  const int wave = threadIdx.x >> 6;
  const int lane = threadIdx.x & 63;

  float upacc = 0.0f;
  for (int row = blockIdx.x * 4 + wave; row < 8192; row += 2048) {
    const int uidx = user[row];
    const int pidx = pos[row];
    float uv = uw[uidx * EMB + lane];
    float pv = iw[pidx * EMB + lane];

    float us = uv * uv, ps = pv * pv;
    #pragma unroll
    for (int off = 32; off; off >>= 1) {
      us += __shfl_xor(us, off);
      ps += __shfl_xor(ps, off);
    }
    const float un = uv / fmaxf(sqrtf(us), 1e-12f);
    const float pn = pv / fmaxf(sqrtf(ps), 1e-12f);
    u_bf[row * EMB + lane] = __float2bfloat16(un);
    p_bf[row * EMB + lane] = __float2bfloat16(pn);

    float ipv = un * pn;
    #pragma unroll
    for (int off = 32; off; off >>= 1) ipv += __shfl_xor(ipv, off);

    if (lane == 0) {
      uflag[uidx] = 1;
      iflag[pidx] = 1;
      const float t = ipv * C5LOG2E;
      upacc += logf(EXP2_HW(t) + EXP2_HW(ipv * t));  // log(exp(ip/T)+exp(ip^2/T))
    }
  }

  __shared__ float sred[4];
  if (lane == 0) sred[wave] = upacc;
  __syncthreads();
  if (threadIdx.x == 0)
    up_partials[blockIdx.x] = (sred[0] + sred[1]) + (sred[2] + sred[3]);
}

// 1024 blocks; each handles 4 consecutive 128x128 tiles in one row-strip
// (by = blk>>4, bx = (blk&15)*4 .. +3). A-fragments loaded ONCE per wave and
// reused across the 4 tiles (halves L2 traffic, amortizes load latency).
// 4 waves in 2x2 per tile; per-tile: load B frags -> 32 MFMA -> exp epilogue.
__global__ __launch_bounds__(256) void gemm_kernel(
    const __hip_bfloat16* __restrict__ U, const __hip_bfloat16* __restrict__ P,
    float* __restrict__ down_partials)
{
  const int by  = blockIdx.x >> 4;
  const int bx0 = (blockIdx.x & 15) << 2;
  const int wave = threadIdx.x >> 6;
  const int lane = threadIdx.x & 63;
  const int r0 = by * 128 + (wave >> 1) * 64;
  const int lrow = lane & 15;
  const int lk   = (lane >> 4) * 8;

  short8 a[4][2];
  #pragma unroll
  for (int i = 0; i < 4; ++i)
    #pragma unroll
    for (int kk = 0; kk < 2; ++kk)
      a[i][kk] = *reinterpret_cast<const short8*>(
          &U[(size_t)(r0 + i * 16 + lrow) * EMB + kk * 32 + lk]);

  float s0 = 0.0f, s1 = 0.0f;

  for (int t = 0; t < 4; ++t) {
    const int c0 = (bx0 + t) * 128 + (wave & 1) * 64;

    short8 b[4][2];
    #pragma unroll
    for (int j = 0; j < 4; ++j)
      #pragma unroll
      for (int kk = 0; kk < 2; ++kk)
        b[j][kk] = *reinterpret_cast<const short8*>(
            &P[(size_t)(c0 + j * 16 + lrow) * EMB + kk * 32 + lk]);

    f32x4 acc[4][4] = {};
    #pragma unroll
    for (int i = 0; i < 4; ++i)
      #pragma unroll
      for (int j = 0; j < 4; ++j) {
        acc[i][j] = mfma16x16x32(a[i][0], b[j][0], acc[i][j]);
        acc[i][j] = mfma16x16x32(a[i][1], b[j][1], acc[i][j]);
      }

    // exp(v/T) = 2^(v*C); exp(v^2/T) = 2^(v*(v*C)); |v| <= ~1 so no range issues.
    #pragma unroll
    for (int i = 0; i < 4; ++i)
      #pragma unroll
      for (int j = 0; j < 4; ++j)
        #pragma unroll
        for (int r = 0; r < 4; ++r) {
          const float v = acc[i][j][r];
          const float tt = v * C5LOG2E;
          s0 += EXP2_HW(tt);
          s1 += EXP2_HW(v * tt);
        }
  }

  float s = s0 + s1;
  #pragma unroll
  for (int off = 32; off; off >>= 1) s += __shfl_xor(s, off);

  __shared__ float sred[4];
  if (lane == 0) sred[wave] = s;
  __syncthreads();
  if (threadIdx.x == 0)
    down_partials[blockIdx.x] = (sred[0] + sred[1]) + (sred[2] + sred[3]);
}

// Single-block deterministic final reduction (shuffle-based).
__global__ __launch_bounds__(1024) void finalize_kernel(
    const float* __restrict__ up_partials, const float* __restrict__ down_partials,
    const uint4* __restrict__ uflag4, const uint4* __restrict__ iflag4,
    float* __restrict__ out)
{
  const int tid  = threadIdx.x;
  const int wave = tid >> 6;
  const int lane = tid & 63;

  float upv = (tid < 512) ? up_partials[tid] : 0.0f;
  float dnv = down_partials[tid];              // exactly 1024 partials
  int uc = 0, ic = 0;
  for (int i = tid; i < 6250; i += 1024) {     // 100000 bytes = 6250 * 16
    uint4 v = uflag4[i];
    uc += __popc(v.x) + __popc(v.y) + __popc(v.z) + __popc(v.w);
    uint4 w = iflag4[i];
    ic += __popc(w.x) + __popc(w.y) + __popc(w.z) + __popc(w.w);
  }

  #pragma unroll
  for (int off = 32; off; off >>= 1) {
    upv += __shfl_xor(upv, off);
    dnv += __shfl_xor(dnv, off);
    uc  += __shfl_xor(uc, off);
    ic  += __shfl_xor(ic, off);
  }

  __shared__ float sf[2][16];
  __shared__ int   si[2][16];
  if (lane == 0) { sf[0][wave] = upv; sf[1][wave] = dnv; si[0][wave] = uc; si[1][wave] = ic; }
  __syncthreads();
  if (tid == 0) {
    float usum = 0.0f, dsum = 0.0f; int nu = 0, ni = 0;
    #pragma unroll
    for (int w = 0; w < 16; ++w) {
      usum += sf[0][w]; dsum += sf[1][w]; nu += si[0][w]; ni += si[1][w];
    }
    out[0] = -(usum / 8192.0f);
    out[1] = logf(dsum / ((float)nu * (float)ni));
  }
}

extern "C" void kernel_launch(void* const* d_in, const int* in_sizes, int n_in,
                              void* d_out, int out_size, void* d_ws, size_t ws_size,
                              hipStream_t stream) {
  const int*   user = (const int*)d_in[0];
  const int*   pos  = (const int*)d_in[1];
  // d_in[2] = negative (unused by the reference loss)
  const float* uw   = (const float*)d_in[3];
  const float* iw   = (const float*)d_in[4];
  float* out = (float*)d_out;

  char* ws = (char*)d_ws;
  __hip_bfloat16* u_bf = (__hip_bfloat16*)(ws);
  __hip_bfloat16* p_bf = (__hip_bfloat16*)(ws + (1u << 20));
  unsigned char*  uflag = (unsigned char*)(ws + (2u << 20));
  unsigned char*  iflag = uflag + 100000;                    // offsets stay 16B aligned
  float* up_partials   = (float*)(ws + (2u << 20) + 200000);
  float* down_partials = up_partials + 512;

  clear_kernel<<<49, 256, 0, stream>>>((uint4*)uflag);       // clears uflag+iflag (200 KB)
  prep_kernel<<<512, 256, 0, stream>>>(user, pos, uw, iw, u_bf, p_bf,
                                       uflag, iflag, up_partials);
  gemm_kernel<<<1024, 256, 0, stream>>>(u_bf, p_bf, down_partials);
  finalize_kernel<<<1, 1024, 0, stream>>>(up_partials, down_partials,
                                          (const uint4*)uflag, (const uint4*)iflag, out);
}